// Round 12
// baseline (832.557 us; speedup 1.0000x reference)
//
#include <hip/hip_runtime.h>
#include <hip/hip_bf16.h>
#include <cstdint>
#include <cstddef>

// ---------------------------------------------------------------------------
// SectorMultiHeadTransformerAllocator: 2-layer transformer encoder + head
// B=4 T=2048 F=512 D=1024 H=16 dh=64 L=2 DFF=4096 G=16
// R12: ALL GEMMs at (128,128) tiles (2 blocks/CU) per the measured
//      2-barrier-structure tile sweep (128^2 912 TF > 256-class 792).
//      Attn/LN/converts unchanged from R11.
// ---------------------------------------------------------------------------

typedef __bf16 bf16_t;
typedef __attribute__((ext_vector_type(8))) __bf16 bf16x8;
typedef __attribute__((ext_vector_type(4))) __bf16 bf16x4;
typedef __attribute__((ext_vector_type(4))) float f32x4;
typedef __attribute__((ext_vector_type(16))) float f32x16;
typedef __attribute__((ext_vector_type(2))) unsigned u32x2;
typedef __attribute__((ext_vector_type(4))) unsigned u32x4;

#define DEV __device__ __forceinline__
#define AS1 __attribute__((address_space(1)))
#define AS3 __attribute__((address_space(3)))

DEV void gload_lds16(const void* g, void* l) {
  // async global->LDS, 16B/lane; LDS dest = wave-uniform base + lane*16
  __builtin_amdgcn_global_load_lds((AS1 void*)(g), (AS3 void*)(l), 16, 0, 0);
}

// XOR-swizzled pointer into a row-major LDS tile with 128B rows.
DEV const char* swz_ptr(const void* base, int row, int colb) {
  return (const char*)base + row * 128 + ((((colb >> 4) ^ (row & 7))) << 4) +
         (colb & 15);
}

DEV unsigned cvtpk(float lo, float hi) {
  unsigned r;
  asm("v_cvt_pk_bf16_f32 %0, %1, %2" : "=v"(r) : "v"(lo), "v"(hi));
  return r;
}
DEV void swap32(unsigned& a, unsigned& b) {
  u32x2 r = __builtin_amdgcn_permlane32_swap(a, b, false, false);
  a = r[0];
  b = r[1];
}
DEV bf16x8 mkfrag(unsigned w0, unsigned w1, unsigned w2, unsigned w3) {
  u32x4 v = {w0, w1, w2, w3};
  return __builtin_bit_cast(bf16x8, v);
}

// ---------------------------------------------------------------------------
// merged fp32->bf16 convert of ALL inputs; each block = 1024 elems.
// segment table (blocks): x 4096 | proj_w 512 | qkv 6x1024 | wo 2048 |
// w1 8192 | w2 8192  => 29184 blocks total.
// ---------------------------------------------------------------------------
__global__ __launch_bounds__(256) void convert_all(
    const float* __restrict__ x, const float* __restrict__ proj_w,
    const float* __restrict__ wq, const float* __restrict__ wk,
    const float* __restrict__ wvv, const float* __restrict__ wo,
    const float* __restrict__ w1, const float* __restrict__ w2,
    bf16_t* __restrict__ x16, bf16_t* __restrict__ pw16,
    bf16_t* __restrict__ wqkv16, bf16_t* __restrict__ wo16,
    bf16_t* __restrict__ w1_16, bf16_t* __restrict__ w2_16) {
  const int blk = blockIdx.x, tid = threadIdx.x;
  const float* s;
  bf16_t* d;
  if (blk < 4096) {
    s = x + (size_t)blk * 1024;
    d = x16 + (size_t)blk * 1024;
  } else if (blk < 4608) {
    const int q = blk - 4096;
    s = proj_w + (size_t)q * 1024;
    d = pw16 + (size_t)q * 1024;
  } else if (blk < 10752) {
    const int q = blk - 4608;
    const int sub = q >> 10, off = q & 1023;  // sub = l*3+p
    const int l = sub / 3, p = sub - l * 3;
    const float* base = (p == 0) ? wq : ((p == 1) ? wk : wvv);
    s = base + (size_t)l * 1048576 + (size_t)off * 1024;
    d = wqkv16 + (size_t)sub * 1048576 + (size_t)off * 1024;
  } else if (blk < 12800) {
    const int q = blk - 10752;
    s = wo + (size_t)q * 1024;
    d = wo16 + (size_t)q * 1024;
  } else if (blk < 20992) {
    const int q = blk - 12800;
    s = w1 + (size_t)q * 1024;
    d = w1_16 + (size_t)q * 1024;
  } else {
    const int q = blk - 20992;
    s = w2 + (size_t)q * 1024;
    d = w2_16 + (size_t)q * 1024;
  }
  const float4 v = *(const float4*)&s[tid * 4];
  bf16x4 o = {(bf16_t)v.x, (bf16_t)v.y, (bf16_t)v.z, (bf16_t)v.w};
  *(bf16x4*)&d[tid * 4] = o;
}

// concat bias for fused QKV: out[l*3072 + p*1024 + i] = b_p[l*1024 + i]
__global__ __launch_bounds__(256) void bcat_kernel(const float* __restrict__ bq,
                                                   const float* __restrict__ bk,
                                                   const float* __restrict__ bv,
                                                   float* __restrict__ out) {
  const int idx = blockIdx.x * 256 + threadIdx.x;  // 6144
  const int l = idx / 3072, r = idx - l * 3072;
  const int p = r >> 10, i = r & 1023;
  const float* s = (p == 0) ? bq : ((p == 1) ? bk : bv);
  out[idx] = s[l * 1024 + i];
}

// ---------------------------------------------------------------------------
// positional encoding table: pe[t*1024 + 2i] = sin(t*div_i), +1 = cos
// ---------------------------------------------------------------------------
__global__ __launch_bounds__(256) void pe_kernel(float* __restrict__ pe) {
  const int idx = blockIdx.x * 256 + threadIdx.x;  // t*512 + i
  const int t = idx >> 9, i = idx & 511;
  const float dv = __expf((float)(2 * i) * -0.008994473019508785f);  // -ln(1e4)/1024
  const float ph = (float)t * dv;
  pe[(size_t)t * 1024 + 2 * i] = sinf(ph);
  pe[(size_t)t * 1024 + 2 * i + 1] = cosf(ph);
}

// ---------------------------------------------------------------------------
// gemm9 (validated 16x16, (128,128) config): C[M,N] = A[M,K] @ W[N,K]^T.
// 256 thr, 4 waves 2Mx2N (wave 64x64, MF=4), LDS 2x32KB -> 2 blocks/CU.
// Double-buffered K-tiles, counted vmcnt (distance 2, never drains mid-loop),
// XOR swizzle both-sides, setprio around MFMA clusters.
// EPI 0:+bias | 1:+bias,relu | 2:+bias+pe | 3:+bias+res16 — all write bf16.
// ---------------------------------------------------------------------------
template <int EPI, int BM, int BN>
__global__ __launch_bounds__(BM == 256 ? 512 : 256, 2) void gemm9(
    const bf16_t* __restrict__ A, const bf16_t* __restrict__ W,
    const float* __restrict__ bias, bf16_t* __restrict__ outb,
    const bf16_t* __restrict__ res16, const float* __restrict__ pe, int M,
    int N, int K) {
  constexpr int T = (BM == 256) ? 512 : 256;
  constexpr int RPC = T / 8;                  // rows per gload call
  constexpr int NA = (BM * 128) / (T * 16);   // A loads/thread/K-tile
  constexpr int NB = (BN * 128) / (T * 16);
  constexpr int LPT = NA + NB;
  constexpr bool WIDE = (BM == 256 && BN == 256);
  constexpr int MF = WIDE ? 8 : 4;
  constexpr int ASZ = BM * 128;
  constexpr int BUFSZ = (BM + BN) * 128;
  __shared__ char smem[2][BUFSZ];
  const int tid = threadIdx.x, wv = tid >> 6, ln = tid & 63;
  const int nwg = gridDim.x * gridDim.y;
  int bid = blockIdx.y * gridDim.x + blockIdx.x;
  bid = (bid & 7) * (nwg >> 3) + (bid >> 3);
  const int m0 = (bid / gridDim.x) * BM, n0 = (bid % gridDim.x) * BN;
  const int wrow = WIDE ? (wv >> 2) * 128 : (wv >> 1) * 64;
  const int wcol = WIDE ? (wv & 3) * 64 : (wv & 1) * 64;
  f32x4 acc[MF][4] = {};

  // staging: pre-swizzled source lane (rule 21 involution)
  const int tp = tid ^ ((tid >> 3) & 7);
  const int srow = tp >> 3, sc8 = (tp & 7) * 8;
  const bf16_t* pa[NA];
  const bf16_t* pb[NB];
#pragma unroll
  for (int u = 0; u < NA; ++u) pa[u] = A + (size_t)(m0 + u * RPC + srow) * K + sc8;
#pragma unroll
  for (int u = 0; u < NB; ++u) pb[u] = W + (size_t)(n0 + u * RPC + srow) * K + sc8;
  const int wvb = wv * 1024;

  auto stage = [&](int s) {
    char* bA = &smem[s][0] + wvb;
    char* bB = &smem[s][ASZ] + wvb;
#pragma unroll
    for (int u = 0; u < NA; ++u) {
      gload_lds16(pa[u], bA + u * (T * 16));
      pa[u] += 64;
    }
#pragma unroll
    for (int u = 0; u < NB; ++u) {
      gload_lds16(pb[u], bB + u * (T * 16));
      pb[u] += 64;
    }
  };

  auto wait_lpt = [&]() {
    if constexpr (LPT == 8)
      asm volatile("s_waitcnt vmcnt(8)" ::: "memory");
    else
      asm volatile("s_waitcnt vmcnt(6)" ::: "memory");
  };

  const int NK = K >> 6;  // >= 8 for all our shapes
  stage(0);
  stage(1);
  wait_lpt();  // tile 0 landed
  __builtin_amdgcn_s_barrier();

  for (int kt = 0; kt < NK; ++kt) {
    const char* bA = &smem[kt & 1][0];
    const char* bB = &smem[kt & 1][ASZ];
#pragma unroll
    for (int ks = 0; ks < 2; ++ks) {
      const int cb = ks * 64 + (ln >> 4) * 16;
      bf16x8 bF[4];
#pragma unroll
      for (int n = 0; n < 4; ++n) {
        const int lb = (wcol + n * 16 + (ln & 15)) * 128 + cb;
        bF[n] = *(const bf16x8*)(bB + (lb ^ (((lb >> 7) & 7) << 4)));
      }
#pragma unroll
      for (int mh = 0; mh < 2; ++mh) {
        bf16x8 aF[MF / 2];
#pragma unroll
        for (int m = 0; m < MF / 2; ++m) {
          const int lb = (wrow + (mh * (MF / 2) + m) * 16 + (ln & 15)) * 128 + cb;
          aF[m] = *(const bf16x8*)(bA + (lb ^ (((lb >> 7) & 7) << 4)));
        }
        __builtin_amdgcn_s_setprio(1);
#pragma unroll
        for (int m = 0; m < MF / 2; ++m)
#pragma unroll
          for (int n = 0; n < 4; ++n)
            acc[mh * (MF / 2) + m][n] = __builtin_amdgcn_mfma_f32_16x16x32_bf16(
                aF[m], bF[n], acc[mh * (MF / 2) + m][n], 0, 0, 0);
        __builtin_amdgcn_s_setprio(0);
      }
    }
    __builtin_amdgcn_s_barrier();  // all reads of smem[kt&1] complete
    if (kt + 2 < NK) {
      stage(kt & 1);  // tile kt+2 into freed buffer
      wait_lpt();     // tile kt+1 landed; kt+2 stays in flight
    } else if (kt + 1 < NK) {
      asm volatile("s_waitcnt vmcnt(0)" ::: "memory");
    }
    __builtin_amdgcn_s_barrier();
    __builtin_amdgcn_sched_barrier(0);
  }

  const int rr = (ln >> 4) * 4, cc = ln & 15;
#pragma unroll
  for (int m = 0; m < MF; ++m) {
    const int rowb = m0 + wrow + m * 16 + rr;
#pragma unroll
    for (int n = 0; n < 4; ++n) {
      const int col = n0 + wcol + n * 16 + cc;
      const float bv = bias[col];
#pragma unroll
      for (int r = 0; r < 4; ++r) {
        const int row = rowb + r;
        float v = acc[m][n][r] + bv;
        const size_t o = (size_t)row * N + col;
        if constexpr (EPI == 1) {
          v = fmaxf(v, 0.f);
        } else if constexpr (EPI == 2) {
          v += pe[(size_t)(row & 2047) * 1024 + col];
        } else if constexpr (EPI == 3) {
          v += (float)res16[o];
        }
        outb[o] = (bf16_t)v;
      }
    }
  }
}

// ---------------------------------------------------------------------------
// LayerNorm over rows of 1024 (bf16 in -> bf16 out)
// ---------------------------------------------------------------------------
__global__ __launch_bounds__(256) void ln_kernel(const bf16_t* __restrict__ pre,
                                                 const float* __restrict__ g,
                                                 const float* __restrict__ b,
                                                 bf16_t* __restrict__ h16) {
  const int row = blockIdx.x, tid = threadIdx.x;
  const size_t base = (size_t)row * 1024 + tid * 4;
  const bf16x4 pv = *(const bf16x4*)&pre[base];
  const float v0 = (float)pv[0], v1 = (float)pv[1], v2 = (float)pv[2],
              v3 = (float)pv[3];
  float s = v0 + v1 + v2 + v3;
  float s2 = v0 * v0 + v1 * v1 + v2 * v2 + v3 * v3;
#pragma unroll
  for (int m = 1; m < 64; m <<= 1) {
    s += __shfl_xor(s, m);
    s2 += __shfl_xor(s2, m);
  }
  __shared__ float ls[4], ls2[4];
  if ((tid & 63) == 0) {
    ls[tid >> 6] = s;
    ls2[tid >> 6] = s2;
  }
  __syncthreads();
  s = ls[0] + ls[1] + ls[2] + ls[3];
  s2 = ls2[0] + ls2[1] + ls2[2] + ls2[3];
  const float mean = s * (1.f / 1024.f);
  const float var = s2 * (1.f / 1024.f) - mean * mean;
  const float rs = rsqrtf(var + 1e-5f);
  const float4 gv = *(const float4*)&g[tid * 4];
  const float4 bv = *(const float4*)&b[tid * 4];
  bf16x4 ob = {(bf16_t)((v0 - mean) * rs * gv.x + bv.x),
               (bf16_t)((v1 - mean) * rs * gv.y + bv.y),
               (bf16_t)((v2 - mean) * rs * gv.z + bv.z),
               (bf16_t)((v3 - mean) * rs * gv.w + bv.w)};
  *(bf16x4*)&h16[base] = ob;
}

// ---------------------------------------------------------------------------
// V transpose from fused qkv: v[(b*T+t)*3072 + h*64 + d] (v = qkv+2048)
//   -> vt[((b*16+h)*64 + d)*2048 + t].  grid (T/64, B*H), 256 thr
// ---------------------------------------------------------------------------
__global__ __launch_bounds__(256) void transpose_v(const bf16_t* __restrict__ v,
                                                   bf16_t* __restrict__ vt) {
  __shared__ bf16_t tile[64][80];
  const int bh = blockIdx.y, t0 = blockIdx.x * 64;
  const int tid = threadIdx.x;
  const int b = bh >> 4;
  const size_t vbase = ((size_t)(b * 2048 + t0)) * 3072 + (bh & 15) * 64;
#pragma unroll
  for (int p = 0; p < 2; ++p) {
    const int chunk = p * 256 + tid;
    const int tr = chunk >> 3, c8 = (chunk & 7) * 8;
    *(bf16x8*)&tile[tr][c8] = *(const bf16x8*)&v[vbase + (size_t)tr * 3072 + c8];
  }
  __syncthreads();
  const int d = tid >> 2, t8 = (tid & 3) * 16;
  bf16_t tmp[16];
#pragma unroll
  for (int j = 0; j < 16; ++j) tmp[j] = tile[t8 + j][d];
  const size_t obase = ((size_t)bh * 64 + d) * 2048 + t0 + t8;
  *(bf16x8*)&vt[obase] = *(bf16x8*)&tmp[0];
  *(bf16x8*)&vt[obase + 8] = *(bf16x8*)&tmp[8];
}

// ---------------------------------------------------------------------------
// Flash attention (R10/R11-validated): 32x32x16 MFMA, in-register P, no
// max-tracking (bounded scores), SCL pre-folded into Q fragments.
// grid (T/128=16, B*H=64) XCD-swizzled, 256 thr = 4 waves x 32 q-rows.
// ---------------------------------------------------------------------------
__global__ __launch_bounds__(256, 4) void attn_kernel(const bf16_t* __restrict__ qkv,
                                                      const bf16_t* __restrict__ vt,
                                                      bf16_t* __restrict__ ctx) {
  constexpr float SCL = 0.18033688011112042f;  // (1/8) * log2(e)
  constexpr int QS = 3072;
  __shared__ bf16_t lK[2][64 * 64];  // [s][k]
  __shared__ bf16_t lV[2][64 * 64];  // [d][s]
  const int tid = threadIdx.x, wv = tid >> 6, ln = tid & 63;
  const int nwg = gridDim.x * gridDim.y;  // 1024
  int bid = blockIdx.y * gridDim.x + blockIdx.x;
  bid = (bid & 7) * (nwg >> 3) + (bid >> 3);
  const int bh = bid / gridDim.x, b = bh >> 4, h = bh & 15;
  const int q0 = (bid % gridDim.x) * 128 + wv * 32;
  const int lq = ln & 31, hi = ln >> 5;
  // Q fragments (B-operand), pre-scaled by SCL so exp2 needs no multiply.
  const bf16_t* qp = qkv + (size_t)(b * 2048 + q0 + lq) * QS + h * 64 + hi * 8;
  bf16x8 qF[4];
#pragma unroll
  for (int kk = 0; kk < 4; ++kk) {
    const bf16x8 raw = *(const bf16x8*)(qp + kk * 16);
    unsigned w[4];
#pragma unroll
    for (int j = 0; j < 4; ++j)
      w[j] = cvtpk((float)raw[2 * j] * SCL, (float)raw[2 * j + 1] * SCL);
    qF[kk] = mkfrag(w[0], w[1], w[2], w[3]);
  }
  f32x16 O0 = {}, O1 = {};
  float l_q = 0.f;  // softmax denom for q = lq (dup on partner lanes)
  const int sr = tid >> 3;
  const int scS = ((tid & 7) ^ ((tid >> 3) & 7)) * 8;  // pre-swizzled src col
  const bf16_t* kp0 = qkv + 1024 + (size_t)(b * 2048 + sr) * QS + h * 64 + scS;
  const bf16_t* kp1 = kp0 + (size_t)32 * QS;
  const bf16_t* vp0 = vt + (size_t)bh * 64 * 2048 + (size_t)sr * 2048 + scS;
  const bf16_t* vp1 = vp0 + 32 * 2048;

  auto stage = [&](int bufi) {
    char* dk = (char*)&lK[bufi][0] + wv * 1024;
    char* dv = (char*)&lV[bufi][0] + wv * 1024;
    gload_lds16(kp0, dk);
    gload_lds16(kp1, dk + 4096);
    gload_lds16(vp0, dv);
    gload_lds16(vp1, dv + 4096);
    kp0 += (size_t)64 * QS;
    kp1 += (size_t)64 * QS;
    vp0 += 64;
    vp1 += 64;
  };

  stage(0);
  asm volatile("s_waitcnt vmcnt(0)" ::: "memory");
  __builtin_amdgcn_s_barrier();

  for (int st = 0; st < 32; ++st) {
    const int cur = st & 1;
    if (st + 1 < 32) stage(cur ^ 1);  // prefetch next tile (overlaps compute)
#pragma unroll
    for (int sb = 0; sb < 2; ++sb) {
      // --- QK^T for s rows sb*32..sb*32+31 (col q = lq); S pre-scaled
      f32x16 s = {};
      __builtin_amdgcn_s_setprio(1);
#pragma unroll
      for (int kk = 0; kk < 4; ++kk) {
        const bf16x8 kf =
            *(const bf16x8*)swz_ptr(&lK[cur][0], sb * 32 + lq, kk * 32 + hi * 16);
        s = __builtin_amdgcn_mfma_f32_32x32x16_bf16(kf, qF[kk], s, 0, 0, 0);
      }
      __builtin_amdgcn_s_setprio(0);
      // --- P = exp2(S) (no max subtraction: bounded scores)
      float ra = 0.f, rb = 0.f;
#pragma unroll
      for (int i = 0; i < 8; ++i) {
        s[i] = exp2f(s[i]);
        ra += s[i];
        s[i + 8] = exp2f(s[i + 8]);
        rb += s[i + 8];
      }
      float rsum = ra + rb;
      rsum += __shfl_xor(rsum, 32);
      l_q += rsum;
      // --- pack P -> 2 A-frags (8 cvt_pk + 4 permlane32_swap)
      unsigned A = cvtpk(s[0], s[1]), Bq = cvtpk(s[2], s[3]);
      unsigned C = cvtpk(s[4], s[5]), Dq = cvtpk(s[6], s[7]);
      unsigned A2 = cvtpk(s[8], s[9]), B2 = cvtpk(s[10], s[11]);
      unsigned C2 = cvtpk(s[12], s[13]), D2 = cvtpk(s[14], s[15]);
      swap32(A, C);
      swap32(Bq, Dq);
      swap32(A2, C2);
      swap32(B2, D2);
      const bf16x8 f0 = mkfrag(A, Bq, C, Dq);
      const bf16x8 f1 = mkfrag(A2, B2, C2, D2);
      // --- PV partial: s-chunks 2*sb, 2*sb+1
      __builtin_amdgcn_s_setprio(1);
      const bf16x8 va = *(const bf16x8*)swz_ptr(&lV[cur][0], lq, sb * 64 + hi * 16);
      const bf16x8 vb =
          *(const bf16x8*)swz_ptr(&lV[cur][0], lq, sb * 64 + 32 + hi * 16);
      const bf16x8 vc =
          *(const bf16x8*)swz_ptr(&lV[cur][0], 32 + lq, sb * 64 + hi * 16);
      const bf16x8 vd =
          *(const bf16x8*)swz_ptr(&lV[cur][0], 32 + lq, sb * 64 + 32 + hi * 16);
      O0 = __builtin_amdgcn_mfma_f32_32x32x16_bf16(f0, va, O0, 0, 0, 0);
      O0 = __builtin_amdgcn_mfma_f32_32x32x16_bf16(f1, vb, O0, 0, 0, 0);
      O1 = __builtin_amdgcn_mfma_f32_32x32x16_bf16(f0, vc, O1, 0, 0, 0);
      O1 = __builtin_amdgcn_mfma_f32_32x32x16_bf16(f1, vd, O1, 0, 0, 0);
      __builtin_amdgcn_s_setprio(0);
    }
    asm volatile("s_waitcnt vmcnt(0)" ::: "memory");  // next tile landed
    __builtin_amdgcn_s_barrier();
    __builtin_amdgcn_sched_barrier(0);
  }
  // --- epilogue: O[q][d] / l[q];  row q = (r&3)+8*(r>>2)+4*hi, col d = lq
  const float invl = 1.f / l_q;
  const size_t obase = ((size_t)(b * 2048 + q0)) * 1024 + h * 64 + lq;
#pragma unroll
  for (int r = 0; r < 16; ++r) {
    const int qr = (r & 3) + 8 * (r >> 2) + 4 * hi;
    const float iv = __shfl(invl, qr);
    ctx[obase + (size_t)qr * 1024] = (bf16_t)(O0[r] * iv);
    ctx[obase + (size_t)qr * 1024 + 32] = (bf16_t)(O1[r] * iv);
  }
}

// ---------------------------------------------------------------------------
// Head part 1: z[b,g,k] = relu(hl[b,:] . hw1[g,k,:] + hb1[g,k]);  hl = h16
// last rows (bf16). grid (G=16, 16 k-slabs of 64), 256 thr.
// ---------------------------------------------------------------------------
__global__ __launch_bounds__(256) void head_z(const bf16_t* __restrict__ h16,
                                              const float* __restrict__ hw1,
                                              const float* __restrict__ hb1,
                                              float* __restrict__ z) {
  const int g = blockIdx.x, slab = blockIdx.y;
  const int wv = threadIdx.x >> 6, ln = threadIdx.x & 63;
  float4 hl[4][4];
#pragma unroll
  for (int b = 0; b < 4; ++b)
#pragma unroll
    for (int c = 0; c < 4; ++c) {
      const bf16x4 hv = *(const bf16x4*)&h16[((size_t)b * 2048 + 2047) * 1024 +
                                             c * 256 + ln * 4];
      hl[b][c] = make_float4((float)hv[0], (float)hv[1], (float)hv[2], (float)hv[3]);
    }
  const int k0 = slab * 64 + wv * 16;
  for (int kk = 0; kk < 16; ++kk) {
    const int kq = k0 + kk;
    const float* wrow = hw1 + ((size_t)g * 1024 + kq) * 1024;
    float p[4] = {0, 0, 0, 0};
#pragma unroll
    for (int c = 0; c < 4; ++c) {
      const float4 w4 = *(const float4*)&wrow[c * 256 + ln * 4];
#pragma unroll
      for (int b = 0; b < 4; ++b)
        p[b] += w4.x * hl[b][c].x + w4.y * hl[b][c].y + w4.z * hl[b][c].z +
                w4.w * hl[b][c].w;
    }
#pragma unroll
    for (int m = 1; m < 64; m <<= 1)
#pragma unroll
      for (int b = 0; b < 4; ++b) p[b] += __shfl_xor(p[b], m);
    if (ln == 0) {
#pragma unroll
      for (int b = 0; b < 4; ++b)
        z[((size_t)b * 16 + g) * 1024 + kq] = fmaxf(p[b] + hb1[g * 1024 + kq], 0.f);
    }
  }
}

// ---------------------------------------------------------------------------
// Head part 2: logits + 2-way softmax. grid (4,16), 64 thr.
// ---------------------------------------------------------------------------
__global__ __launch_bounds__(64) void head_logits(const float* __restrict__ z,
                                                  const float* __restrict__ hw2,
                                                  const float* __restrict__ hb2,
                                                  float* __restrict__ out) {
  const int b = blockIdx.x, g = blockIdx.y, ln = threadIdx.x;
  const float* zr = z + ((size_t)b * 16 + g) * 1024;
  const float* w0 = hw2 + (size_t)g * 2048;
  const float* w1 = w0 + 1024;
  float p0 = 0.f, p1 = 0.f;
#pragma unroll
  for (int c = 0; c < 4; ++c) {
    const float4 zv = *(const float4*)&zr[c * 256 + ln * 4];
    const float4 a0 = *(const float4*)&w0[c * 256 + ln * 4];
    const float4 a1 = *(const float4*)&w1[c * 256 + ln * 4];
    p0 += zv.x * a0.x + zv.y * a0.y + zv.z * a0.z + zv.w * a0.w;
    p1 += zv.x * a1.x + zv.y * a1.y + zv.z * a1.z + zv.w * a1.w;
  }
#pragma unroll
  for (int m = 1; m < 64; m <<= 1) {
    p0 += __shfl_xor(p0, m);
    p1 += __shfl_xor(p1, m);
  }
  if (ln == 0) {
    const float l0 = p0 + hb2[g * 2], l1 = p1 + hb2[g * 2 + 1];
    const float mx = fmaxf(l0, l1);
    const float e0 = expf(l0 - mx), e1 = expf(l1 - mx);
    const float inv = 1.f / (e0 + e1);
    out[(size_t)b * 32 + g * 2] = e0 * inv;
    out[(size_t)b * 32 + g * 2 + 1] = e1 * inv;
  }
}

// ---------------------------------------------------------------------------
extern "C" void kernel_launch(void* const* d_in, const int* in_sizes, int n_in,
                              void* d_out, int out_size, void* d_ws, size_t ws_size,
                              hipStream_t stream) {
  const float* x = (const float*)d_in[0];
  const float* proj_w = (const float*)d_in[1];
  const float* proj_b = (const float*)d_in[2];
  const float* wq = (const float*)d_in[3];
  const float* wk = (const float*)d_in[4];
  const float* wvv = (const float*)d_in[5];
  const float* bq = (const float*)d_in[6];
  const float* bk = (const float*)d_in[7];
  const float* bv = (const float*)d_in[8];
  const float* wo = (const float*)d_in[9];
  const float* bo = (const float*)d_in[10];
  const float* ln1_g = (const float*)d_in[11];
  const float* ln1_b = (const float*)d_in[12];
  const float* ln2_g = (const float*)d_in[13];
  const float* ln2_b = (const float*)d_in[14];
  const float* w1 = (const float*)d_in[15];
  const float* b1 = (const float*)d_in[16];
  const float* w2 = (const float*)d_in[17];
  const float* b2 = (const float*)d_in[18];
  const float* hw1 = (const float*)d_in[19];
  const float* hb1 = (const float*)d_in[20];
  const float* hw2 = (const float*)d_in[21];
  const float* hb2 = (const float*)d_in[22];
  float* out = (float*)d_out;
  char* ws = (char*)d_ws;

  // ---- workspace layout (bytes), lifetime-aliased ----
  size_t o = 0;
  auto take = [&](size_t bytes) { size_t r = o; o += bytes; return r; };
  const size_t o_wqkv = take(12582912);  // L*3072*1024 bf16 (q|k|v rows)
  const size_t o_wo = take(4194304);
  const size_t o_w1 = take(16777216);
  const size_t o_w2 = take(16777216);
  const size_t o_pw = take(1048576);
  const size_t o_h16 = take(16777216);
  const size_t o_pre = take(16777216);  // pre-LN, bf16
  const size_t o_r4 = take(67108864);   // {qkv(50.3M), vT(8.4M)} | ff1(64M)
  const size_t o_r5 = take(16777216);   // {x16, pe} | ctx
  const size_t o_z = take(262144);
  const size_t o_bqkv = take(24576);

  bf16_t* wqkv16 = (bf16_t*)(ws + o_wqkv);
  bf16_t* wo16 = (bf16_t*)(ws + o_wo);
  bf16_t* w1_16 = (bf16_t*)(ws + o_w1);
  bf16_t* w2_16 = (bf16_t*)(ws + o_w2);
  bf16_t* pw16 = (bf16_t*)(ws + o_pw);
  bf16_t* h16 = (bf16_t*)(ws + o_h16);
  bf16_t* pre16 = (bf16_t*)(ws + o_pre);
  bf16_t* qkv16 = (bf16_t*)(ws + o_r4);
  bf16_t* vT16 = (bf16_t*)(ws + o_r4 + 50331648);
  bf16_t* ff1 = (bf16_t*)(ws + o_r4);
  bf16_t* x16 = (bf16_t*)(ws + o_r5);
  float* pe32 = (float*)(ws + o_r5 + 8388608);
  bf16_t* ctx16 = (bf16_t*)(ws + o_r5);
  float* zbuf = (float*)(ws + o_z);
  float* bqkv = (float*)(ws + o_bqkv);

  // ---- merged conversion + PE table + bias concat ----
  convert_all<<<29184, 256, 0, stream>>>(x, proj_w, wq, wk, wvv, wo, w1, w2, x16,
                                         pw16, wqkv16, wo16, w1_16, w2_16);
  bcat_kernel<<<24, 256, 0, stream>>>(bq, bk, bv, bqkv);
  pe_kernel<<<4096, 256, 0, stream>>>(pe32);

  // ---- projection: h = x @ proj_w^T + proj_b + pe ----
  gemm9<2, 128, 128><<<dim3(8, 64), 256, 0, stream>>>(x16, pw16, proj_b, h16, nullptr,
                                                      pe32, 8192, 1024, 512);

  for (int l = 0; l < 2; ++l) {
    const bf16_t* wqkv_l = wqkv16 + (size_t)l * 3145728;
    const bf16_t* wo_l = wo16 + (size_t)l * 1048576;
    const bf16_t* w1_l = w1_16 + (size_t)l * 4194304;
    const bf16_t* w2_l = w2_16 + (size_t)l * 4194304;

    gemm9<0, 128, 128><<<dim3(24, 64), 256, 0, stream>>>(h16, wqkv_l, bqkv + l * 3072,
                                                         qkv16, nullptr, nullptr, 8192,
                                                         3072, 1024);
    transpose_v<<<dim3(32, 64), 256, 0, stream>>>(qkv16 + 2048, vT16);
    attn_kernel<<<dim3(16, 64), 256, 0, stream>>>(qkv16, vT16, ctx16);
    gemm9<3, 128, 128><<<dim3(8, 64), 256, 0, stream>>>(ctx16, wo_l, bo + l * 1024,
                                                        pre16, h16, nullptr, 8192,
                                                        1024, 1024);
    ln_kernel<<<8192, 256, 0, stream>>>(pre16, ln1_g + l * 1024, ln1_b + l * 1024,
                                        h16);
    gemm9<1, 128, 128><<<dim3(32, 64), 256, 0, stream>>>(h16, w1_l, b1 + l * 4096, ff1,
                                                         nullptr, nullptr, 8192, 4096,
                                                         1024);
    gemm9<3, 128, 128><<<dim3(8, 64), 256, 0, stream>>>(ff1, w2_l, b2 + l * 1024,
                                                        pre16, h16, nullptr, 8192,
                                                        1024, 4096);
    ln_kernel<<<8192, 256, 0, stream>>>(pre16, ln2_g + l * 1024, ln2_b + l * 1024,
                                        h16);
  }

  // ---- head ----
  head_z<<<dim3(16, 16), 256, 0, stream>>>(h16, hw1, hb1, zbuf);
  head_logits<<<dim3(4, 16), 64, 0, stream>>>(zbuf, hw2, hb2, out);
}

// Round 13
// 811.568 us; speedup vs baseline: 1.0259x; 1.0259x over previous
//
#include <hip/hip_runtime.h>
#include <hip/hip_bf16.h>
#include <cstdint>
#include <cstddef>

// ---------------------------------------------------------------------------
// SectorMultiHeadTransformerAllocator: 2-layer transformer encoder + head
// B=4 T=2048 F=512 D=1024 H=16 dh=64 L=2 DFF=4096 G=16
// R13: revert R12's tile change (regressed): QKV=(256,128), FF1=(256,256),
//      N=1024 GEMMs=(128,128) — the best-measured R11 configuration.
//      pe/bcat merged into the convert kernel (3 launches -> 1).
// ---------------------------------------------------------------------------

typedef __bf16 bf16_t;
typedef __attribute__((ext_vector_type(8))) __bf16 bf16x8;
typedef __attribute__((ext_vector_type(4))) __bf16 bf16x4;
typedef __attribute__((ext_vector_type(4))) float f32x4;
typedef __attribute__((ext_vector_type(16))) float f32x16;
typedef __attribute__((ext_vector_type(2))) unsigned u32x2;
typedef __attribute__((ext_vector_type(4))) unsigned u32x4;

#define DEV __device__ __forceinline__
#define AS1 __attribute__((address_space(1)))
#define AS3 __attribute__((address_space(3)))

DEV void gload_lds16(const void* g, void* l) {
  // async global->LDS, 16B/lane; LDS dest = wave-uniform base + lane*16
  __builtin_amdgcn_global_load_lds((AS1 void*)(g), (AS3 void*)(l), 16, 0, 0);
}

// XOR-swizzled pointer into a row-major LDS tile with 128B rows.
DEV const char* swz_ptr(const void* base, int row, int colb) {
  return (const char*)base + row * 128 + ((((colb >> 4) ^ (row & 7))) << 4) +
         (colb & 15);
}

DEV unsigned cvtpk(float lo, float hi) {
  unsigned r;
  asm("v_cvt_pk_bf16_f32 %0, %1, %2" : "=v"(r) : "v"(lo), "v"(hi));
  return r;
}
DEV void swap32(unsigned& a, unsigned& b) {
  u32x2 r = __builtin_amdgcn_permlane32_swap(a, b, false, false);
  a = r[0];
  b = r[1];
}
DEV bf16x8 mkfrag(unsigned w0, unsigned w1, unsigned w2, unsigned w3) {
  u32x4 v = {w0, w1, w2, w3};
  return __builtin_bit_cast(bf16x8, v);
}

// ---------------------------------------------------------------------------
// merged prep kernel: fp32->bf16 converts (29184 blocks) + PE table (4096)
// + qkv bias concat (24). One launch, 33304 blocks x 256 thr.
// ---------------------------------------------------------------------------
__global__ __launch_bounds__(256) void prep_all(
    const float* __restrict__ x, const float* __restrict__ proj_w,
    const float* __restrict__ wq, const float* __restrict__ wk,
    const float* __restrict__ wvv, const float* __restrict__ wo,
    const float* __restrict__ w1, const float* __restrict__ w2,
    const float* __restrict__ bq, const float* __restrict__ bk,
    const float* __restrict__ bv, bf16_t* __restrict__ x16,
    bf16_t* __restrict__ pw16, bf16_t* __restrict__ wqkv16,
    bf16_t* __restrict__ wo16, bf16_t* __restrict__ w1_16,
    bf16_t* __restrict__ w2_16, float* __restrict__ pe,
    float* __restrict__ bqkv) {
  const int blk = blockIdx.x, tid = threadIdx.x;
  if (blk >= 29184) {
    if (blk >= 33280) {  // bias concat: 24 blocks
      const int idx = (blk - 33280) * 256 + tid;  // 6144
      const int l = idx / 3072, r = idx - l * 3072;
      const int p = r >> 10, i = r & 1023;
      const float* s = (p == 0) ? bq : ((p == 1) ? bk : bv);
      bqkv[idx] = s[l * 1024 + i];
      return;
    }
    // PE table: 4096 blocks; idx = t*512 + i
    const int idx = (blk - 29184) * 256 + tid;
    const int t = idx >> 9, i = idx & 511;
    const float dv = __expf((float)(2 * i) * -0.008994473019508785f);
    const float ph = (float)t * dv;
    pe[(size_t)t * 1024 + 2 * i] = sinf(ph);
    pe[(size_t)t * 1024 + 2 * i + 1] = cosf(ph);
    return;
  }
  const float* s;
  bf16_t* d;
  if (blk < 4096) {
    s = x + (size_t)blk * 1024;
    d = x16 + (size_t)blk * 1024;
  } else if (blk < 4608) {
    const int q = blk - 4096;
    s = proj_w + (size_t)q * 1024;
    d = pw16 + (size_t)q * 1024;
  } else if (blk < 10752) {
    const int q = blk - 4608;
    const int sub = q >> 10, off = q & 1023;  // sub = l*3+p
    const int l = sub / 3, p = sub - l * 3;
    const float* base = (p == 0) ? wq : ((p == 1) ? wk : wvv);
    s = base + (size_t)l * 1048576 + (size_t)off * 1024;
    d = wqkv16 + (size_t)sub * 1048576 + (size_t)off * 1024;
  } else if (blk < 12800) {
    const int q = blk - 10752;
    s = wo + (size_t)q * 1024;
    d = wo16 + (size_t)q * 1024;
  } else if (blk < 20992) {
    const int q = blk - 12800;
    s = w1 + (size_t)q * 1024;
    d = w1_16 + (size_t)q * 1024;
  } else {
    const int q = blk - 20992;
    s = w2 + (size_t)q * 1024;
    d = w2_16 + (size_t)q * 1024;
  }
  const float4 v = *(const float4*)&s[tid * 4];
  bf16x4 o = {(bf16_t)v.x, (bf16_t)v.y, (bf16_t)v.z, (bf16_t)v.w};
  *(bf16x4*)&d[tid * 4] = o;
}

// ---------------------------------------------------------------------------
// gemm9 (R11-validated): C[M,N] = A[M,K] @ W[N,K]^T + epilogue.
// (BM,BN)=(256,256): 512 thr, 8 waves 2Mx4N (wave 128x64, MF=8), LDS 2x64KB.
// (BM,BN)=(256,128): 512 thr, 8 waves 4Mx2N (wave  64x64, MF=4), LDS 2x48KB.
// (BM,BN)=(128,128): 256 thr, 4 waves 2Mx2N (wave  64x64, MF=4), LDS 2x32KB.
// Double-buffered K-tiles, counted vmcnt (distance 2, never drains mid-loop),
// XOR swizzle both-sides, setprio around MFMA clusters.
// EPI 0:+bias | 1:+bias,relu | 2:+bias+pe | 3:+bias+res16 — all write bf16.
// ---------------------------------------------------------------------------
template <int EPI, int BM, int BN>
__global__ __launch_bounds__(BM == 256 ? 512 : 256, 2) void gemm9(
    const bf16_t* __restrict__ A, const bf16_t* __restrict__ W,
    const float* __restrict__ bias, bf16_t* __restrict__ outb,
    const bf16_t* __restrict__ res16, const float* __restrict__ pe, int M,
    int N, int K) {
  constexpr int T = (BM == 256) ? 512 : 256;
  constexpr int RPC = T / 8;                  // rows per gload call
  constexpr int NA = (BM * 128) / (T * 16);   // A loads/thread/K-tile
  constexpr int NB = (BN * 128) / (T * 16);
  constexpr int LPT = NA + NB;
  constexpr bool WIDE = (BM == 256 && BN == 256);
  constexpr int MF = WIDE ? 8 : 4;
  constexpr int ASZ = BM * 128;
  constexpr int BUFSZ = (BM + BN) * 128;
  __shared__ char smem[2][BUFSZ];
  const int tid = threadIdx.x, wv = tid >> 6, ln = tid & 63;
  const int nwg = gridDim.x * gridDim.y;
  int bid = blockIdx.y * gridDim.x + blockIdx.x;
  bid = (bid & 7) * (nwg >> 3) + (bid >> 3);
  const int m0 = (bid / gridDim.x) * BM, n0 = (bid % gridDim.x) * BN;
  const int wrow = WIDE ? (wv >> 2) * 128 : (wv >> 1) * 64;
  const int wcol = WIDE ? (wv & 3) * 64 : (wv & 1) * 64;
  f32x4 acc[MF][4] = {};

  // staging: pre-swizzled source lane (rule 21 involution)
  const int tp = tid ^ ((tid >> 3) & 7);
  const int srow = tp >> 3, sc8 = (tp & 7) * 8;
  const bf16_t* pa[NA];
  const bf16_t* pb[NB];
#pragma unroll
  for (int u = 0; u < NA; ++u) pa[u] = A + (size_t)(m0 + u * RPC + srow) * K + sc8;
#pragma unroll
  for (int u = 0; u < NB; ++u) pb[u] = W + (size_t)(n0 + u * RPC + srow) * K + sc8;
  const int wvb = wv * 1024;

  auto stage = [&](int s) {
    char* bA = &smem[s][0] + wvb;
    char* bB = &smem[s][ASZ] + wvb;
#pragma unroll
    for (int u = 0; u < NA; ++u) {
      gload_lds16(pa[u], bA + u * (T * 16));
      pa[u] += 64;
    }
#pragma unroll
    for (int u = 0; u < NB; ++u) {
      gload_lds16(pb[u], bB + u * (T * 16));
      pb[u] += 64;
    }
  };

  auto wait_lpt = [&]() {
    if constexpr (LPT == 8)
      asm volatile("s_waitcnt vmcnt(8)" ::: "memory");
    else
      asm volatile("s_waitcnt vmcnt(6)" ::: "memory");
  };

  const int NK = K >> 6;  // >= 8 for all our shapes
  stage(0);
  stage(1);
  wait_lpt();  // tile 0 landed
  __builtin_amdgcn_s_barrier();

  for (int kt = 0; kt < NK; ++kt) {
    const char* bA = &smem[kt & 1][0];
    const char* bB = &smem[kt & 1][ASZ];
#pragma unroll
    for (int ks = 0; ks < 2; ++ks) {
      const int cb = ks * 64 + (ln >> 4) * 16;
      bf16x8 bF[4];
#pragma unroll
      for (int n = 0; n < 4; ++n) {
        const int lb = (wcol + n * 16 + (ln & 15)) * 128 + cb;
        bF[n] = *(const bf16x8*)(bB + (lb ^ (((lb >> 7) & 7) << 4)));
      }
#pragma unroll
      for (int mh = 0; mh < 2; ++mh) {
        bf16x8 aF[MF / 2];
#pragma unroll
        for (int m = 0; m < MF / 2; ++m) {
          const int lb = (wrow + (mh * (MF / 2) + m) * 16 + (ln & 15)) * 128 + cb;
          aF[m] = *(const bf16x8*)(bA + (lb ^ (((lb >> 7) & 7) << 4)));
        }
        __builtin_amdgcn_s_setprio(1);
#pragma unroll
        for (int m = 0; m < MF / 2; ++m)
#pragma unroll
          for (int n = 0; n < 4; ++n)
            acc[mh * (MF / 2) + m][n] = __builtin_amdgcn_mfma_f32_16x16x32_bf16(
                aF[m], bF[n], acc[mh * (MF / 2) + m][n], 0, 0, 0);
        __builtin_amdgcn_s_setprio(0);
      }
    }
    __builtin_amdgcn_s_barrier();  // all reads of smem[kt&1] complete
    if (kt + 2 < NK) {
      stage(kt & 1);  // tile kt+2 into freed buffer
      wait_lpt();     // tile kt+1 landed; kt+2 stays in flight
    } else if (kt + 1 < NK) {
      asm volatile("s_waitcnt vmcnt(0)" ::: "memory");
    }
    __builtin_amdgcn_s_barrier();
    __builtin_amdgcn_sched_barrier(0);
  }

  const int rr = (ln >> 4) * 4, cc = ln & 15;
#pragma unroll
  for (int m = 0; m < MF; ++m) {
    const int rowb = m0 + wrow + m * 16 + rr;
#pragma unroll
    for (int n = 0; n < 4; ++n) {
      const int col = n0 + wcol + n * 16 + cc;
      const float bv = bias[col];
#pragma unroll
      for (int r = 0; r < 4; ++r) {
        const int row = rowb + r;
        float v = acc[m][n][r] + bv;
        const size_t o = (size_t)row * N + col;
        if constexpr (EPI == 1) {
          v = fmaxf(v, 0.f);
        } else if constexpr (EPI == 2) {
          v += pe[(size_t)(row & 2047) * 1024 + col];
        } else if constexpr (EPI == 3) {
          v += (float)res16[o];
        }
        outb[o] = (bf16_t)v;
      }
    }
  }
}

// ---------------------------------------------------------------------------
// LayerNorm over rows of 1024 (bf16 in -> bf16 out)
// ---------------------------------------------------------------------------
__global__ __launch_bounds__(256) void ln_kernel(const bf16_t* __restrict__ pre,
                                                 const float* __restrict__ g,
                                                 const float* __restrict__ b,
                                                 bf16_t* __restrict__ h16) {
  const int row = blockIdx.x, tid = threadIdx.x;
  const size_t base = (size_t)row * 1024 + tid * 4;
  const bf16x4 pv = *(const bf16x4*)&pre[base];
  const float v0 = (float)pv[0], v1 = (float)pv[1], v2 = (float)pv[2],
              v3 = (float)pv[3];
  float s = v0 + v1 + v2 + v3;
  float s2 = v0 * v0 + v1 * v1 + v2 * v2 + v3 * v3;
#pragma unroll
  for (int m = 1; m < 64; m <<= 1) {
    s += __shfl_xor(s, m);
    s2 += __shfl_xor(s2, m);
  }
  __shared__ float ls[4], ls2[4];
  if ((tid & 63) == 0) {
    ls[tid >> 6] = s;
    ls2[tid >> 6] = s2;
  }
  __syncthreads();
  s = ls[0] + ls[1] + ls[2] + ls[3];
  s2 = ls2[0] + ls2[1] + ls2[2] + ls2[3];
  const float mean = s * (1.f / 1024.f);
  const float var = s2 * (1.f / 1024.f) - mean * mean;
  const float rs = rsqrtf(var + 1e-5f);
  const float4 gv = *(const float4*)&g[tid * 4];
  const float4 bv = *(const float4*)&b[tid * 4];
  bf16x4 ob = {(bf16_t)((v0 - mean) * rs * gv.x + bv.x),
               (bf16_t)((v1 - mean) * rs * gv.y + bv.y),
               (bf16_t)((v2 - mean) * rs * gv.z + bv.z),
               (bf16_t)((v3 - mean) * rs * gv.w + bv.w)};
  *(bf16x4*)&h16[base] = ob;
}

// ---------------------------------------------------------------------------
// V transpose from fused qkv: v[(b*T+t)*3072 + h*64 + d] (v = qkv+2048)
//   -> vt[((b*16+h)*64 + d)*2048 + t].  grid (T/64, B*H), 256 thr
// ---------------------------------------------------------------------------
__global__ __launch_bounds__(256) void transpose_v(const bf16_t* __restrict__ v,
                                                   bf16_t* __restrict__ vt) {
  __shared__ bf16_t tile[64][80];
  const int bh = blockIdx.y, t0 = blockIdx.x * 64;
  const int tid = threadIdx.x;
  const int b = bh >> 4;
  const size_t vbase = ((size_t)(b * 2048 + t0)) * 3072 + (bh & 15) * 64;
#pragma unroll
  for (int p = 0; p < 2; ++p) {
    const int chunk = p * 256 + tid;
    const int tr = chunk >> 3, c8 = (chunk & 7) * 8;
    *(bf16x8*)&tile[tr][c8] = *(const bf16x8*)&v[vbase + (size_t)tr * 3072 + c8];
  }
  __syncthreads();
  const int d = tid >> 2, t8 = (tid & 3) * 16;
  bf16_t tmp[16];
#pragma unroll
  for (int j = 0; j < 16; ++j) tmp[j] = tile[t8 + j][d];
  const size_t obase = ((size_t)bh * 64 + d) * 2048 + t0 + t8;
  *(bf16x8*)&vt[obase] = *(bf16x8*)&tmp[0];
  *(bf16x8*)&vt[obase + 8] = *(bf16x8*)&tmp[8];
}

// ---------------------------------------------------------------------------
// Flash attention (R10/R11-validated): 32x32x16 MFMA, in-register P, no
// max-tracking (bounded scores), SCL pre-folded into Q fragments.
// grid (T/128=16, B*H=64) XCD-swizzled, 256 thr = 4 waves x 32 q-rows.
// ---------------------------------------------------------------------------
__global__ __launch_bounds__(256, 4) void attn_kernel(const bf16_t* __restrict__ qkv,
                                                      const bf16_t* __restrict__ vt,
                                                      bf16_t* __restrict__ ctx) {
  constexpr float SCL = 0.18033688011112042f;  // (1/8) * log2(e)
  constexpr int QS = 3072;
  __shared__ bf16_t lK[2][64 * 64];  // [s][k]
  __shared__ bf16_t lV[2][64 * 64];  // [d][s]
  const int tid = threadIdx.x, wv = tid >> 6, ln = tid & 63;
  const int nwg = gridDim.x * gridDim.y;  // 1024
  int bid = blockIdx.y * gridDim.x + blockIdx.x;
  bid = (bid & 7) * (nwg >> 3) + (bid >> 3);
  const int bh = bid / gridDim.x, b = bh >> 4, h = bh & 15;
  const int q0 = (bid % gridDim.x) * 128 + wv * 32;
  const int lq = ln & 31, hi = ln >> 5;
  // Q fragments (B-operand), pre-scaled by SCL so exp2 needs no multiply.
  const bf16_t* qp = qkv + (size_t)(b * 2048 + q0 + lq) * QS + h * 64 + hi * 8;
  bf16x8 qF[4];
#pragma unroll
  for (int kk = 0; kk < 4; ++kk) {
    const bf16x8 raw = *(const bf16x8*)(qp + kk * 16);
    unsigned w[4];
#pragma unroll
    for (int j = 0; j < 4; ++j)
      w[j] = cvtpk((float)raw[2 * j] * SCL, (float)raw[2 * j + 1] * SCL);
    qF[kk] = mkfrag(w[0], w[1], w[2], w[3]);
  }
  f32x16 O0 = {}, O1 = {};
  float l_q = 0.f;  // softmax denom for q = lq (dup on partner lanes)
  const int sr = tid >> 3;
  const int scS = ((tid & 7) ^ ((tid >> 3) & 7)) * 8;  // pre-swizzled src col
  const bf16_t* kp0 = qkv + 1024 + (size_t)(b * 2048 + sr) * QS + h * 64 + scS;
  const bf16_t* kp1 = kp0 + (size_t)32 * QS;
  const bf16_t* vp0 = vt + (size_t)bh * 64 * 2048 + (size_t)sr * 2048 + scS;
  const bf16_t* vp1 = vp0 + 32 * 2048;

  auto stage = [&](int bufi) {
    char* dk = (char*)&lK[bufi][0] + wv * 1024;
    char* dv = (char*)&lV[bufi][0] + wv * 1024;
    gload_lds16(kp0, dk);
    gload_lds16(kp1, dk + 4096);
    gload_lds16(vp0, dv);
    gload_lds16(vp1, dv + 4096);
    kp0 += (size_t)64 * QS;
    kp1 += (size_t)64 * QS;
    vp0 += 64;
    vp1 += 64;
  };

  stage(0);
  asm volatile("s_waitcnt vmcnt(0)" ::: "memory");
  __builtin_amdgcn_s_barrier();

  for (int st = 0; st < 32; ++st) {
    const int cur = st & 1;
    if (st + 1 < 32) stage(cur ^ 1);  // prefetch next tile (overlaps compute)
#pragma unroll
    for (int sb = 0; sb < 2; ++sb) {
      // --- QK^T for s rows sb*32..sb*32+31 (col q = lq); S pre-scaled
      f32x16 s = {};
      __builtin_amdgcn_s_setprio(1);
#pragma unroll
      for (int kk = 0; kk < 4; ++kk) {
        const bf16x8 kf =
            *(const bf16x8*)swz_ptr(&lK[cur][0], sb * 32 + lq, kk * 32 + hi * 16);
        s = __builtin_amdgcn_mfma_f32_32x32x16_bf16(kf, qF[kk], s, 0, 0, 0);
      }
      __builtin_amdgcn_s_setprio(0);
      // --- P = exp2(S) (no max subtraction: bounded scores)
      float ra = 0.f, rb = 0.f;
#pragma unroll
      for (int i = 0; i < 8; ++i) {
        s[i] = exp2f(s[i]);
        ra += s[i];
        s[i + 8] = exp2f(s[i + 8]);
        rb += s[i + 8];
      }
      float rsum = ra + rb;
      rsum += __shfl_xor(rsum, 32);
      l_q += rsum;
      // --- pack P -> 2 A-frags (8 cvt_pk + 4 permlane32_swap)
      unsigned A = cvtpk(s[0], s[1]), Bq = cvtpk(s[2], s[3]);
      unsigned C = cvtpk(s[4], s[5]), Dq = cvtpk(s[6], s[7]);
      unsigned A2 = cvtpk(s[8], s[9]), B2 = cvtpk(s[10], s[11]);
      unsigned C2 = cvtpk(s[12], s[13]), D2 = cvtpk(s[14], s[15]);
      swap32(A, C);
      swap32(Bq, Dq);
      swap32(A2, C2);
      swap32(B2, D2);
      const bf16x8 f0 = mkfrag(A, Bq, C, Dq);
      const bf16x8 f1 = mkfrag(A2, B2, C2, D2);
      // --- PV partial: s-chunks 2*sb, 2*sb+1
      __builtin_amdgcn_s_setprio(1);
      const bf16x8 va = *(const bf16x8*)swz_ptr(&lV[cur][0], lq, sb * 64 + hi * 16);
      const bf16x8 vb =
          *(const bf16x8*)swz_ptr(&lV[cur][0], lq, sb * 64 + 32 + hi * 16);
      const bf16x8 vc =
          *(const bf16x8*)swz_ptr(&lV[cur][0], 32 + lq, sb * 64 + hi * 16);
      const bf16x8 vd =
          *(const bf16x8*)swz_ptr(&lV[cur][0], 32 + lq, sb * 64 + 32 + hi * 16);
      O0 = __builtin_amdgcn_mfma_f32_32x32x16_bf16(f0, va, O0, 0, 0, 0);
      O0 = __builtin_amdgcn_mfma_f32_32x32x16_bf16(f1, vb, O0, 0, 0, 0);
      O1 = __builtin_amdgcn_mfma_f32_32x32x16_bf16(f0, vc, O1, 0, 0, 0);
      O1 = __builtin_amdgcn_mfma_f32_32x32x16_bf16(f1, vd, O1, 0, 0, 0);
      __builtin_amdgcn_s_setprio(0);
    }
    asm volatile("s_waitcnt vmcnt(0)" ::: "memory");  // next tile landed
    __builtin_amdgcn_s_barrier();
    __builtin_amdgcn_sched_barrier(0);
  }
  // --- epilogue: O[q][d] / l[q];  row q = (r&3)+8*(r>>2)+4*hi, col d = lq
  const float invl = 1.f / l_q;
  const size_t obase = ((size_t)(b * 2048 + q0)) * 1024 + h * 64 + lq;
#pragma unroll
  for (int r = 0; r < 16; ++r) {
    const int qr = (r & 3) + 8 * (r >> 2) + 4 * hi;
    const float iv = __shfl(invl, qr);
    ctx[obase + (size_t)qr * 1024] = (bf16_t)(O0[r] * iv);
    ctx[obase + (size_t)qr * 1024 + 32] = (bf16_t)(O1[r] * iv);
  }
}

// ---------------------------------------------------------------------------
// Head part 1: z[b,g,k] = relu(hl[b,:] . hw1[g,k,:] + hb1[g,k]);  hl = h16
// last rows (bf16). grid (G=16, 16 k-slabs of 64), 256 thr.
// ---------------------------------------------------------------------------
__global__ __launch_bounds__(256) void head_z(const bf16_t* __restrict__ h16,
                                              const float* __restrict__ hw1,
                                              const float* __restrict__ hb1,
                                              float* __restrict__ z) {
  const int g = blockIdx.x, slab = blockIdx.y;
  const int wv = threadIdx.x >> 6, ln = threadIdx.x & 63;
  float4 hl[4][4];
#pragma unroll
  for (int b = 0; b < 4; ++b)
#pragma unroll
    for (int c = 0; c < 4; ++c) {
      const bf16x4 hv = *(const bf16x4*)&h16[((size_t)b * 2048 + 2047) * 1024 +
                                             c * 256 + ln * 4];
      hl[b][c] = make_float4((float)hv[0], (float)hv[1], (float)hv[2], (float)hv[3]);
    }
  const int k0 = slab * 64 + wv * 16;
  for (int kk = 0; kk < 16; ++kk) {
    const int kq = k0 + kk;
    const float* wrow = hw1 + ((size_t)g * 1024 + kq) * 1024;
    float p[4] = {0, 0, 0, 0};
#pragma unroll
    for (int c = 0; c < 4; ++c) {
      const float4 w4 = *(const float4*)&wrow[c * 256 + ln * 4];
#pragma unroll
      for (int b = 0; b < 4; ++b)
        p[b] += w4.x * hl[b][c].x + w4.y * hl[b][c].y + w4.z * hl[b][c].z +
                w4.w * hl[b][c].w;
    }
#pragma unroll
    for (int m = 1; m < 64; m <<= 1)
#pragma unroll
      for (int b = 0; b < 4; ++b) p[b] += __shfl_xor(p[b], m);
    if (ln == 0) {
#pragma unroll
      for (int b = 0; b < 4; ++b)
        z[((size_t)b * 16 + g) * 1024 + kq] = fmaxf(p[b] + hb1[g * 1024 + kq], 0.f);
    }
  }
}

// ---------------------------------------------------------------------------
// Head part 2: logits + 2-way softmax. grid (4,16), 64 thr.
// ---------------------------------------------------------------------------
__global__ __launch_bounds__(64) void head_logits(const float* __restrict__ z,
                                                  const float* __restrict__ hw2,
                                                  const float* __restrict__ hb2,
                                                  float* __restrict__ out) {
  const int b = blockIdx.x, g = blockIdx.y, ln = threadIdx.x;
  const float* zr = z + ((size_t)b * 16 + g) * 1024;
  const float* w0 = hw2 + (size_t)g * 2048;
  const float* w1 = w0 + 1024;
  float p0 = 0.f, p1 = 0.f;
#pragma unroll
  for (int c = 0; c < 4; ++c) {
    const float4 zv = *(const float4*)&zr[c * 256 + ln * 4];
    const float4 a0 = *(const float4*)&w0[c * 256 + ln * 4];
    const float4 a1 = *(const float4*)&w1[c * 256 + ln * 4];
    p0 += zv.x * a0.x + zv.y * a0.y + zv.z * a0.z + zv.w * a0.w;
    p1 += zv.x * a1.x + zv.y * a1.y + zv.z * a1.z + zv.w * a1.w;
  }
#pragma unroll
  for (int m = 1; m < 64; m <<= 1) {
    p0 += __shfl_xor(p0, m);
    p1 += __shfl_xor(p1, m);
  }
  if (ln == 0) {
    const float l0 = p0 + hb2[g * 2], l1 = p1 + hb2[g * 2 + 1];
    const float mx = fmaxf(l0, l1);
    const float e0 = expf(l0 - mx), e1 = expf(l1 - mx);
    const float inv = 1.f / (e0 + e1);
    out[(size_t)b * 32 + g * 2] = e0 * inv;
    out[(size_t)b * 32 + g * 2 + 1] = e1 * inv;
  }
}

// ---------------------------------------------------------------------------
extern "C" void kernel_launch(void* const* d_in, const int* in_sizes, int n_in,
                              void* d_out, int out_size, void* d_ws, size_t ws_size,
                              hipStream_t stream) {
  const float* x = (const float*)d_in[0];
  const float* proj_w = (const float*)d_in[1];
  const float* proj_b = (const float*)d_in[2];
  const float* wq = (const float*)d_in[3];
  const float* wk = (const float*)d_in[4];
  const float* wvv = (const float*)d_in[5];
  const float* bq = (const float*)d_in[6];
  const float* bk = (const float*)d_in[7];
  const float* bv = (const float*)d_in[8];
  const float* wo = (const float*)d_in[9];
  const float* bo = (const float*)d_in[10];
  const float* ln1_g = (const float*)d_in[11];
  const float* ln1_b = (const float*)d_in[12];
  const float* ln2_g = (const float*)d_in[13];
  const float* ln2_b = (const float*)d_in[14];
  const float* w1 = (const float*)d_in[15];
  const float* b1 = (const float*)d_in[16];
  const float* w2 = (const float*)d_in[17];
  const float* b2 = (const float*)d_in[18];
  const float* hw1 = (const float*)d_in[19];
  const float* hb1 = (const float*)d_in[20];
  const float* hw2 = (const float*)d_in[21];
  const float* hb2 = (const float*)d_in[22];
  float* out = (float*)d_out;
  char* ws = (char*)d_ws;

  // ---- workspace layout (bytes), lifetime-aliased ----
  size_t o = 0;
  auto take = [&](size_t bytes) { size_t r = o; o += bytes; return r; };
  const size_t o_wqkv = take(12582912);  // L*3072*1024 bf16 (q|k|v rows)
  const size_t o_wo = take(4194304);
  const size_t o_w1 = take(16777216);
  const size_t o_w2 = take(16777216);
  const size_t o_pw = take(1048576);
  const size_t o_h16 = take(16777216);
  const size_t o_pre = take(16777216);  // pre-LN, bf16
  const size_t o_r4 = take(67108864);   // {qkv(50.3M), vT(8.4M)} | ff1(64M)
  const size_t o_r5 = take(16777216);   // {x16, pe} | ctx
  const size_t o_z = take(262144);
  const size_t o_bqkv = take(24576);

  bf16_t* wqkv16 = (bf16_t*)(ws + o_wqkv);
  bf16_t* wo16 = (bf16_t*)(ws + o_wo);
  bf16_t* w1_16 = (bf16_t*)(ws + o_w1);
  bf16_t* w2_16 = (bf16_t*)(ws + o_w2);
  bf16_t* pw16 = (bf16_t*)(ws + o_pw);
  bf16_t* h16 = (bf16_t*)(ws + o_h16);
  bf16_t* pre16 = (bf16_t*)(ws + o_pre);
  bf16_t* qkv16 = (bf16_t*)(ws + o_r4);
  bf16_t* vT16 = (bf16_t*)(ws + o_r4 + 50331648);
  bf16_t* ff1 = (bf16_t*)(ws + o_r4);
  bf16_t* x16 = (bf16_t*)(ws + o_r5);
  float* pe32 = (float*)(ws + o_r5 + 8388608);
  bf16_t* ctx16 = (bf16_t*)(ws + o_r5);
  float* zbuf = (float*)(ws + o_z);
  float* bqkv = (float*)(ws + o_bqkv);

  // ---- merged prep: converts + PE + bias concat (one launch) ----
  prep_all<<<33304, 256, 0, stream>>>(x, proj_w, wq, wk, wvv, wo, w1, w2, bq, bk, bv,
                                      x16, pw16, wqkv16, wo16, w1_16, w2_16, pe32,
                                      bqkv);

  // ---- projection: h = x @ proj_w^T + proj_b + pe ----
  gemm9<2, 128, 128><<<dim3(8, 64), 256, 0, stream>>>(x16, pw16, proj_b, h16, nullptr,
                                                      pe32, 8192, 1024, 512);

  for (int l = 0; l < 2; ++l) {
    const bf16_t* wqkv_l = wqkv16 + (size_t)l * 3145728;
    const bf16_t* wo_l = wo16 + (size_t)l * 1048576;
    const bf16_t* w1_l = w1_16 + (size_t)l * 4194304;
    const bf16_t* w2_l = w2_16 + (size_t)l * 4194304;

    gemm9<0, 256, 128><<<dim3(24, 32), 512, 0, stream>>>(h16, wqkv_l, bqkv + l * 3072,
                                                         qkv16, nullptr, nullptr, 8192,
                                                         3072, 1024);
    transpose_v<<<dim3(32, 64), 256, 0, stream>>>(qkv16 + 2048, vT16);
    attn_kernel<<<dim3(16, 64), 256, 0, stream>>>(qkv16, vT16, ctx16);
    gemm9<3, 128, 128><<<dim3(8, 64), 256, 0, stream>>>(ctx16, wo_l, bo + l * 1024,
                                                        pre16, h16, nullptr, 8192,
                                                        1024, 1024);
    ln_kernel<<<8192, 256, 0, stream>>>(pre16, ln1_g + l * 1024, ln1_b + l * 1024,
                                        h16);
    gemm9<1, 256, 256><<<dim3(16, 32), 512, 0, stream>>>(h16, w1_l, b1 + l * 4096, ff1,
                                                         nullptr, nullptr, 8192, 4096,
                                                         1024);
    gemm9<3, 128, 128><<<dim3(8, 64), 256, 0, stream>>>(ff1, w2_l, b2 + l * 1024,
                                                        pre16, h16, nullptr, 8192,
                                                        1024, 4096);
    ln_kernel<<<8192, 256, 0, stream>>>(pre16, ln2_g + l * 1024, ln2_b + l * 1024,
                                        h16);
  }

  // ---- head ----
  head_z<<<dim3(16, 16), 256, 0, stream>>>(h16, hw1, hb1, zbuf);
  head_logits<<<dim3(4, 16), 64, 0, stream>>>(zbuf, hw2, hb2, out);
}

// Round 14
// 801.972 us; speedup vs baseline: 1.0381x; 1.0120x over previous
//
#include <hip/hip_runtime.h>
#include <hip/hip_bf16.h>
#include <cstdint>
#include <cstddef>

// ---------------------------------------------------------------------------
// SectorMultiHeadTransformerAllocator: 2-layer transformer encoder + head
// B=4 T=2048 F=512 D=1024 H=16 dh=64 L=2 DFF=4096 G=16
// R14: V-transpose fused into QKV GEMM epilogue (EPI=4): V columns written
//      directly as vt[bh,d,t] (bf16x4, t-contiguous). transpose_v deleted;
//      V never written to qkv16. Rest identical to R13 (best measured).
// ---------------------------------------------------------------------------

typedef __bf16 bf16_t;
typedef __attribute__((ext_vector_type(8))) __bf16 bf16x8;
typedef __attribute__((ext_vector_type(4))) __bf16 bf16x4;
typedef __attribute__((ext_vector_type(4))) float f32x4;
typedef __attribute__((ext_vector_type(16))) float f32x16;
typedef __attribute__((ext_vector_type(2))) unsigned u32x2;
typedef __attribute__((ext_vector_type(4))) unsigned u32x4;

#define DEV __device__ __forceinline__
#define AS1 __attribute__((address_space(1)))
#define AS3 __attribute__((address_space(3)))

DEV void gload_lds16(const void* g, void* l) {
  // async global->LDS, 16B/lane; LDS dest = wave-uniform base + lane*16
  __builtin_amdgcn_global_load_lds((AS1 void*)(g), (AS3 void*)(l), 16, 0, 0);
}

// XOR-swizzled pointer into a row-major LDS tile with 128B rows.
DEV const char* swz_ptr(const void* base, int row, int colb) {
  return (const char*)base + row * 128 + ((((colb >> 4) ^ (row & 7))) << 4) +
         (colb & 15);
}

DEV unsigned cvtpk(float lo, float hi) {
  unsigned r;
  asm("v_cvt_pk_bf16_f32 %0, %1, %2" : "=v"(r) : "v"(lo), "v"(hi));
  return r;
}
DEV void swap32(unsigned& a, unsigned& b) {
  u32x2 r = __builtin_amdgcn_permlane32_swap(a, b, false, false);
  a = r[0];
  b = r[1];
}
DEV bf16x8 mkfrag(unsigned w0, unsigned w1, unsigned w2, unsigned w3) {
  u32x4 v = {w0, w1, w2, w3};
  return __builtin_bit_cast(bf16x8, v);
}

// ---------------------------------------------------------------------------
// merged prep kernel: fp32->bf16 converts (29184 blocks) + PE table (4096)
// + qkv bias concat (24). One launch, 33304 blocks x 256 thr.
// ---------------------------------------------------------------------------
__global__ __launch_bounds__(256) void prep_all(
    const float* __restrict__ x, const float* __restrict__ proj_w,
    const float* __restrict__ wq, const float* __restrict__ wk,
    const float* __restrict__ wvv, const float* __restrict__ wo,
    const float* __restrict__ w1, const float* __restrict__ w2,
    const float* __restrict__ bq, const float* __restrict__ bk,
    const float* __restrict__ bv, bf16_t* __restrict__ x16,
    bf16_t* __restrict__ pw16, bf16_t* __restrict__ wqkv16,
    bf16_t* __restrict__ wo16, bf16_t* __restrict__ w1_16,
    bf16_t* __restrict__ w2_16, float* __restrict__ pe,
    float* __restrict__ bqkv) {
  const int blk = blockIdx.x, tid = threadIdx.x;
  if (blk >= 29184) {
    if (blk >= 33280) {  // bias concat: 24 blocks
      const int idx = (blk - 33280) * 256 + tid;  // 6144
      const int l = idx / 3072, r = idx - l * 3072;
      const int p = r >> 10, i = r & 1023;
      const float* s = (p == 0) ? bq : ((p == 1) ? bk : bv);
      bqkv[idx] = s[l * 1024 + i];
      return;
    }
    // PE table: 4096 blocks; idx = t*512 + i
    const int idx = (blk - 29184) * 256 + tid;
    const int t = idx >> 9, i = idx & 511;
    const float dv = __expf((float)(2 * i) * -0.008994473019508785f);
    const float ph = (float)t * dv;
    pe[(size_t)t * 1024 + 2 * i] = sinf(ph);
    pe[(size_t)t * 1024 + 2 * i + 1] = cosf(ph);
    return;
  }
  const float* s;
  bf16_t* d;
  if (blk < 4096) {
    s = x + (size_t)blk * 1024;
    d = x16 + (size_t)blk * 1024;
  } else if (blk < 4608) {
    const int q = blk - 4096;
    s = proj_w + (size_t)q * 1024;
    d = pw16 + (size_t)q * 1024;
  } else if (blk < 10752) {
    const int q = blk - 4608;
    const int sub = q >> 10, off = q & 1023;  // sub = l*3+p
    const int l = sub / 3, p = sub - l * 3;
    const float* base = (p == 0) ? wq : ((p == 1) ? wk : wvv);
    s = base + (size_t)l * 1048576 + (size_t)off * 1024;
    d = wqkv16 + (size_t)sub * 1048576 + (size_t)off * 1024;
  } else if (blk < 12800) {
    const int q = blk - 10752;
    s = wo + (size_t)q * 1024;
    d = wo16 + (size_t)q * 1024;
  } else if (blk < 20992) {
    const int q = blk - 12800;
    s = w1 + (size_t)q * 1024;
    d = w1_16 + (size_t)q * 1024;
  } else {
    const int q = blk - 20992;
    s = w2 + (size_t)q * 1024;
    d = w2_16 + (size_t)q * 1024;
  }
  const float4 v = *(const float4*)&s[tid * 4];
  bf16x4 o = {(bf16_t)v.x, (bf16_t)v.y, (bf16_t)v.z, (bf16_t)v.w};
  *(bf16x4*)&d[tid * 4] = o;
}

// ---------------------------------------------------------------------------
// gemm9 (R13-validated): C[M,N] = A[M,K] @ W[N,K]^T + epilogue.
// (BM,BN)=(256,256): 512 thr, 8 waves 2Mx4N (wave 128x64, MF=8), LDS 2x64KB.
// (BM,BN)=(256,128): 512 thr, 8 waves 4Mx2N (wave  64x64, MF=4), LDS 2x48KB.
// (BM,BN)=(128,128): 256 thr, 4 waves 2Mx2N (wave  64x64, MF=4), LDS 2x32KB.
// Double-buffered K-tiles, counted vmcnt (distance 2, never drains mid-loop),
// XOR swizzle both-sides, setprio around MFMA clusters.
// EPI 0:+bias | 1:+bias,relu | 2:+bias+pe | 3:+bias+res16 | 4: QKV fused —
//   cols<2048 (q,k) -> outb row-major; cols>=2048 (v) -> outv[bh,d,t]
//   transposed, one bf16x4 store (t-contiguous). All write bf16.
// ---------------------------------------------------------------------------
template <int EPI, int BM, int BN>
__global__ __launch_bounds__(BM == 256 ? 512 : 256, 2) void gemm9(
    const bf16_t* __restrict__ A, const bf16_t* __restrict__ W,
    const float* __restrict__ bias, bf16_t* __restrict__ outb,
    const bf16_t* __restrict__ res16, const float* __restrict__ pe,
    bf16_t* __restrict__ outv, int M, int N, int K) {
  constexpr int T = (BM == 256) ? 512 : 256;
  constexpr int RPC = T / 8;                  // rows per gload call
  constexpr int NA = (BM * 128) / (T * 16);   // A loads/thread/K-tile
  constexpr int NB = (BN * 128) / (T * 16);
  constexpr int LPT = NA + NB;
  constexpr bool WIDE = (BM == 256 && BN == 256);
  constexpr int MF = WIDE ? 8 : 4;
  constexpr int ASZ = BM * 128;
  constexpr int BUFSZ = (BM + BN) * 128;
  __shared__ char smem[2][BUFSZ];
  const int tid = threadIdx.x, wv = tid >> 6, ln = tid & 63;
  const int nwg = gridDim.x * gridDim.y;
  int bid = blockIdx.y * gridDim.x + blockIdx.x;
  bid = (bid & 7) * (nwg >> 3) + (bid >> 3);
  const int m0 = (bid / gridDim.x) * BM, n0 = (bid % gridDim.x) * BN;
  const int wrow = WIDE ? (wv >> 2) * 128 : (wv >> 1) * 64;
  const int wcol = WIDE ? (wv & 3) * 64 : (wv & 1) * 64;
  f32x4 acc[MF][4] = {};

  // staging: pre-swizzled source lane (rule 21 involution)
  const int tp = tid ^ ((tid >> 3) & 7);
  const int srow = tp >> 3, sc8 = (tp & 7) * 8;
  const bf16_t* pa[NA];
  const bf16_t* pb[NB];
#pragma unroll
  for (int u = 0; u < NA; ++u) pa[u] = A + (size_t)(m0 + u * RPC + srow) * K + sc8;
#pragma unroll
  for (int u = 0; u < NB; ++u) pb[u] = W + (size_t)(n0 + u * RPC + srow) * K + sc8;
  const int wvb = wv * 1024;

  auto stage = [&](int s) {
    char* bA = &smem[s][0] + wvb;
    char* bB = &smem[s][ASZ] + wvb;
#pragma unroll
    for (int u = 0; u < NA; ++u) {
      gload_lds16(pa[u], bA + u * (T * 16));
      pa[u] += 64;
    }
#pragma unroll
    for (int u = 0; u < NB; ++u) {
      gload_lds16(pb[u], bB + u * (T * 16));
      pb[u] += 64;
    }
  };

  auto wait_lpt = [&]() {
    if constexpr (LPT == 8)
      asm volatile("s_waitcnt vmcnt(8)" ::: "memory");
    else
      asm volatile("s_waitcnt vmcnt(6)" ::: "memory");
  };

  const int NK = K >> 6;  // >= 8 for all our shapes
  stage(0);
  stage(1);
  wait_lpt();  // tile 0 landed
  __builtin_amdgcn_s_barrier();

  for (int kt = 0; kt < NK; ++kt) {
    const char* bA = &smem[kt & 1][0];
    const char* bB = &smem[kt & 1][ASZ];
#pragma unroll
    for (int ks = 0; ks < 2; ++ks) {
      const int cb = ks * 64 + (ln >> 4) * 16;
      bf16x8 bF[4];
#pragma unroll
      for (int n = 0; n < 4; ++n) {
        const int lb = (wcol + n * 16 + (ln & 15)) * 128 + cb;
        bF[n] = *(const bf16x8*)(bB + (lb ^ (((lb >> 7) & 7) << 4)));
      }
#pragma unroll
      for (int mh = 0; mh < 2; ++mh) {
        bf16x8 aF[MF / 2];
#pragma unroll
        for (int m = 0; m < MF / 2; ++m) {
          const int lb = (wrow + (mh * (MF / 2) + m) * 16 + (ln & 15)) * 128 + cb;
          aF[m] = *(const bf16x8*)(bA + (lb ^ (((lb >> 7) & 7) << 4)));
        }
        __builtin_amdgcn_s_setprio(1);
#pragma unroll
        for (int m = 0; m < MF / 2; ++m)
#pragma unroll
          for (int n = 0; n < 4; ++n)
            acc[mh * (MF / 2) + m][n] = __builtin_amdgcn_mfma_f32_16x16x32_bf16(
                aF[m], bF[n], acc[mh * (MF / 2) + m][n], 0, 0, 0);
        __builtin_amdgcn_s_setprio(0);
      }
    }
    __builtin_amdgcn_s_barrier();  // all reads of smem[kt&1] complete
    if (kt + 2 < NK) {
      stage(kt & 1);  // tile kt+2 into freed buffer
      wait_lpt();     // tile kt+1 landed; kt+2 stays in flight
    } else if (kt + 1 < NK) {
      asm volatile("s_waitcnt vmcnt(0)" ::: "memory");
    }
    __builtin_amdgcn_s_barrier();
    __builtin_amdgcn_sched_barrier(0);
  }

  const int rr = (ln >> 4) * 4, cc = ln & 15;
#pragma unroll
  for (int m = 0; m < MF; ++m) {
    const int rowb = m0 + wrow + m * 16 + rr;  // multiple of 4
#pragma unroll
    for (int n = 0; n < 4; ++n) {
      const int col = n0 + wcol + n * 16 + cc;
      const float bv = bias[col];
      if constexpr (EPI == 4) {
        if (col < 2048) {
#pragma unroll
          for (int r = 0; r < 4; ++r)
            outb[(size_t)(rowb + r) * N + col] = (bf16_t)(acc[m][n][r] + bv);
        } else {
          // V column: write transposed vt[((b*16+h)*64+d)*2048 + t], t-contig
          bf16x4 pack;
#pragma unroll
          for (int r = 0; r < 4; ++r) pack[r] = (bf16_t)(acc[m][n][r] + bv);
          const int vc = col - 2048;
          const int bb = rowb >> 11, tt = rowb & 2047;
          *(bf16x4*)&outv[(((size_t)bb * 16 + (vc >> 6)) * 64 + (vc & 63)) * 2048 +
                          tt] = pack;
        }
      } else {
#pragma unroll
        for (int r = 0; r < 4; ++r) {
          const int row = rowb + r;
          float v = acc[m][n][r] + bv;
          const size_t o = (size_t)row * N + col;
          if constexpr (EPI == 1) {
            v = fmaxf(v, 0.f);
          } else if constexpr (EPI == 2) {
            v += pe[(size_t)(row & 2047) * 1024 + col];
          } else if constexpr (EPI == 3) {
            v += (float)res16[o];
          }
          outb[o] = (bf16_t)v;
        }
      }
    }
  }
}

// ---------------------------------------------------------------------------
// LayerNorm over rows of 1024 (bf16 in -> bf16 out)
// ---------------------------------------------------------------------------
__global__ __launch_bounds__(256) void ln_kernel(const bf16_t* __restrict__ pre,
                                                 const float* __restrict__ g,
                                                 const float* __restrict__ b,
                                                 bf16_t* __restrict__ h16) {
  const int row = blockIdx.x, tid = threadIdx.x;
  const size_t base = (size_t)row * 1024 + tid * 4;
  const bf16x4 pv = *(const bf16x4*)&pre[base];
  const float v0 = (float)pv[0], v1 = (float)pv[1], v2 = (float)pv[2],
              v3 = (float)pv[3];
  float s = v0 + v1 + v2 + v3;
  float s2 = v0 * v0 + v1 * v1 + v2 * v2 + v3 * v3;
#pragma unroll
  for (int m = 1; m < 64; m <<= 1) {
    s += __shfl_xor(s, m);
    s2 += __shfl_xor(s2, m);
  }
  __shared__ float ls[4], ls2[4];
  if ((tid & 63) == 0) {
    ls[tid >> 6] = s;
    ls2[tid >> 6] = s2;
  }
  __syncthreads();
  s = ls[0] + ls[1] + ls[2] + ls[3];
  s2 = ls2[0] + ls2[1] + ls2[2] + ls2[3];
  const float mean = s * (1.f / 1024.f);
  const float var = s2 * (1.f / 1024.f) - mean * mean;
  const float rs = rsqrtf(var + 1e-5f);
  const float4 gv = *(const float4*)&g[tid * 4];
  const float4 bv = *(const float4*)&b[tid * 4];
  bf16x4 ob = {(bf16_t)((v0 - mean) * rs * gv.x + bv.x),
               (bf16_t)((v1 - mean) * rs * gv.y + bv.y),
               (bf16_t)((v2 - mean) * rs * gv.z + bv.z),
               (bf16_t)((v3 - mean) * rs * gv.w + bv.w)};
  *(bf16x4*)&h16[base] = ob;
}

// ---------------------------------------------------------------------------
// Flash attention (R10/R13-validated): 32x32x16 MFMA, in-register P, no
// max-tracking (bounded scores), SCL pre-folded into Q fragments.
// grid (T/128=16, B*H=64) XCD-swizzled, 256 thr = 4 waves x 32 q-rows.
// ---------------------------------------------------------------------------
__global__ __launch_bounds__(256, 4) void attn_kernel(const bf16_t* __restrict__ qkv,
                                                      const bf16_t* __restrict__ vt,
                                                      bf16_t* __restrict__ ctx) {
  constexpr float SCL = 0.18033688011112042f;  // (1/8) * log2(e)
  constexpr int QS = 3072;
  __shared__ bf16_t lK[2][64 * 64];  // [s][k]
  __shared__ bf16_t lV[2][64 * 64];  // [d][s]
  const int tid = threadIdx.x, wv = tid >> 6, ln = tid & 63;
  const int nwg = gridDim.x * gridDim.y;  // 1024
  int bid = blockIdx.y * gridDim.x + blockIdx.x;
  bid = (bid & 7) * (nwg >> 3) + (bid >> 3);
  const int bh = bid / gridDim.x, b = bh >> 4, h = bh & 15;
  const int q0 = (bid % gridDim.x) * 128 + wv * 32;
  const int lq = ln & 31, hi = ln >> 5;
  // Q fragments (B-operand), pre-scaled by SCL so exp2 needs no multiply.
  const bf16_t* qp = qkv + (size_t)(b * 2048 + q0 + lq) * QS + h * 64 + hi * 8;
  bf16x8 qF[4];
#pragma unroll
  for (int kk = 0; kk < 4; ++kk) {
    const bf16x8 raw = *(const bf16x8*)(qp + kk * 16);
    unsigned w[4];
#pragma unroll
    for (int j = 0; j < 4; ++j)
      w[j] = cvtpk((float)raw[2 * j] * SCL, (float)raw[2 * j + 1] * SCL);
    qF[kk] = mkfrag(w[0], w[1], w[2], w[3]);
  }
  f32x16 O0 = {}, O1 = {};
  float l_q = 0.f;  // softmax denom for q = lq (dup on partner lanes)
  const int sr = tid >> 3;
  const int scS = ((tid & 7) ^ ((tid >> 3) & 7)) * 8;  // pre-swizzled src col
  const bf16_t* kp0 = qkv + 1024 + (size_t)(b * 2048 + sr) * QS + h * 64 + scS;
  const bf16_t* kp1 = kp0 + (size_t)32 * QS;
  const bf16_t* vp0 = vt + (size_t)bh * 64 * 2048 + (size_t)sr * 2048 + scS;
  const bf16_t* vp1 = vp0 + 32 * 2048;

  auto stage = [&](int bufi) {
    char* dk = (char*)&lK[bufi][0] + wv * 1024;
    char* dv = (char*)&lV[bufi][0] + wv * 1024;
    gload_lds16(kp0, dk);
    gload_lds16(kp1, dk + 4096);
    gload_lds16(vp0, dv);
    gload_lds16(vp1, dv + 4096);
    kp0 += (size_t)64 * QS;
    kp1 += (size_t)64 * QS;
    vp0 += 64;
    vp1 += 64;
  };

  stage(0);
  asm volatile("s_waitcnt vmcnt(0)" ::: "memory");
  __builtin_amdgcn_s_barrier();

  for (int st = 0; st < 32; ++st) {
    const int cur = st & 1;
    if (st + 1 < 32) stage(cur ^ 1);  // prefetch next tile (overlaps compute)
#pragma unroll
    for (int sb = 0; sb < 2; ++sb) {
      // --- QK^T for s rows sb*32..sb*32+31 (col q = lq); S pre-scaled
      f32x16 s = {};
      __builtin_amdgcn_s_setprio(1);
#pragma unroll
      for (int kk = 0; kk < 4; ++kk) {
        const bf16x8 kf =
            *(const bf16x8*)swz_ptr(&lK[cur][0], sb * 32 + lq, kk * 32 + hi * 16);
        s = __builtin_amdgcn_mfma_f32_32x32x16_bf16(kf, qF[kk], s, 0, 0, 0);
      }
      __builtin_amdgcn_s_setprio(0);
      // --- P = exp2(S) (no max subtraction: bounded scores)
      float ra = 0.f, rb = 0.f;
#pragma unroll
      for (int i = 0; i < 8; ++i) {
        s[i] = exp2f(s[i]);
        ra += s[i];
        s[i + 8] = exp2f(s[i + 8]);
        rb += s[i + 8];
      }
      float rsum = ra + rb;
      rsum += __shfl_xor(rsum, 32);
      l_q += rsum;
      // --- pack P -> 2 A-frags (8 cvt_pk + 4 permlane32_swap)
      unsigned A = cvtpk(s[0], s[1]), Bq = cvtpk(s[2], s[3]);
      unsigned C = cvtpk(s[4], s[5]), Dq = cvtpk(s[6], s[7]);
      unsigned A2 = cvtpk(s[8], s[9]), B2 = cvtpk(s[10], s[11]);
      unsigned C2 = cvtpk(s[12], s[13]), D2 = cvtpk(s[14], s[15]);
      swap32(A, C);
      swap32(Bq, Dq);
      swap32(A2, C2);
      swap32(B2, D2);
      const bf16x8 f0 = mkfrag(A, Bq, C, Dq);
      const bf16x8 f1 = mkfrag(A2, B2, C2, D2);
      // --- PV partial: s-chunks 2*sb, 2*sb+1
      __builtin_amdgcn_s_setprio(1);
      const bf16x8 va = *(const bf16x8*)swz_ptr(&lV[cur][0], lq, sb * 64 + hi * 16);
      const bf16x8 vb =
          *(const bf16x8*)swz_ptr(&lV[cur][0], lq, sb * 64 + 32 + hi * 16);
      const bf16x8 vc =
          *(const bf16x8*)swz_ptr(&lV[cur][0], 32 + lq, sb * 64 + hi * 16);
      const bf16x8 vd =
          *(const bf16x8*)swz_ptr(&lV[cur][0], 32 + lq, sb * 64 + 32 + hi * 16);
      O0 = __builtin_amdgcn_mfma_f32_32x32x16_bf16(f0, va, O0, 0, 0, 0);
      O0 = __builtin_amdgcn_mfma_f32_32x32x16_bf16(f1, vb, O0, 0, 0, 0);
      O1 = __builtin_amdgcn_mfma_f32_32x32x16_bf16(f0, vc, O1, 0, 0, 0);
      O1 = __builtin_amdgcn_mfma_f32_32x32x16_bf16(f1, vd, O1, 0, 0, 0);
      __builtin_amdgcn_s_setprio(0);
    }
    asm volatile("s_waitcnt vmcnt(0)" ::: "memory");  // next tile landed
    __builtin_amdgcn_s_barrier();
    __builtin_amdgcn_sched_barrier(0);
  }
  // --- epilogue: O[q][d] / l[q];  row q = (r&3)+8*(r>>2)+4*hi, col d = lq
  const float invl = 1.f / l_q;
  const size_t obase = ((size_t)(b * 2048 + q0)) * 1024 + h * 64 + lq;
#pragma unroll
  for (int r = 0; r < 16; ++r) {
    const int qr = (r & 3) + 8 * (r >> 2) + 4 * hi;
    const float iv = __shfl(invl, qr);
    ctx[obase + (size_t)qr * 1024] = (bf16_t)(O0[r] * iv);
    ctx[obase + (size_t)qr * 1024 + 32] = (bf16_t)(O1[r] * iv);
  }
}

// ---------------------------------------------------------------------------
// Head part 1: z[b,g,k] = relu(hl[b,:] . hw1[g,k,:] + hb1[g,k]);  hl = h16
// last rows (bf16). grid (G=16, 16 k-slabs of 64), 256 thr.
// ---------------------------------------------------------------------------
__global__ __launch_bounds__(256) void head_z(const bf16_t* __restrict__ h16,
                                              const float* __restrict__ hw1,
                                              const float* __restrict__ hb1,
                                              float* __restrict__ z) {
  const int g = blockIdx.x, slab = blockIdx.y;
  const int wv = threadIdx.x >> 6, ln = threadIdx.x & 63;
  float4 hl[4][4];
#pragma unroll
  for (int b = 0; b < 4; ++b)
#pragma unroll
    for (int c = 0; c < 4; ++c) {
      const bf16x4 hv = *(const bf16x4*)&h16[((size_t)b * 2048 + 2047) * 1024 +
                                             c * 256 + ln * 4];
      hl[b][c] = make_float4((float)hv[0], (float)hv[1], (float)hv[2], (float)hv[3]);
    }
  const int k0 = slab * 64 + wv * 16;
  for (int kk = 0; kk < 16; ++kk) {
    const int kq = k0 + kk;
    const float* wrow = hw1 + ((size_t)g * 1024 + kq) * 1024;
    float p[4] = {0, 0, 0, 0};
#pragma unroll
    for (int c = 0; c < 4; ++c) {
      const float4 w4 = *(const float4*)&wrow[c * 256 + ln * 4];
#pragma unroll
      for (int b = 0; b < 4; ++b)
        p[b] += w4.x * hl[b][c].x + w4.y * hl[b][c].y + w4.z * hl[b][c].z +
                w4.w * hl[b][c].w;
    }
#pragma unroll
    for (int m = 1; m < 64; m <<= 1)
#pragma unroll
      for (int b = 0; b < 4; ++b) p[b] += __shfl_xor(p[b], m);
    if (ln == 0) {
#pragma unroll
      for (int b = 0; b < 4; ++b)
        z[((size_t)b * 16 + g) * 1024 + kq] = fmaxf(p[b] + hb1[g * 1024 + kq], 0.f);
    }
  }
}

// ---------------------------------------------------------------------------
// Head part 2: logits + 2-way softmax. grid (4,16), 64 thr.
// ---------------------------------------------------------------------------
__global__ __launch_bounds__(64) void head_logits(const float* __restrict__ z,
                                                  const float* __restrict__ hw2,
                                                  const float* __restrict__ hb2,
                                                  float* __restrict__ out) {
  const int b = blockIdx.x, g = blockIdx.y, ln = threadIdx.x;
  const float* zr = z + ((size_t)b * 16 + g) * 1024;
  const float* w0 = hw2 + (size_t)g * 2048;
  const float* w1 = w0 + 1024;
  float p0 = 0.f, p1 = 0.f;
#pragma unroll
  for (int c = 0; c < 4; ++c) {
    const float4 zv = *(const float4*)&zr[c * 256 + ln * 4];
    const float4 a0 = *(const float4*)&w0[c * 256 + ln * 4];
    const float4 a1 = *(const float4*)&w1[c * 256 + ln * 4];
    p0 += zv.x * a0.x + zv.y * a0.y + zv.z * a0.z + zv.w * a0.w;
    p1 += zv.x * a1.x + zv.y * a1.y + zv.z * a1.z + zv.w * a1.w;
  }
#pragma unroll
  for (int m = 1; m < 64; m <<= 1) {
    p0 += __shfl_xor(p0, m);
    p1 += __shfl_xor(p1, m);
  }
  if (ln == 0) {
    const float l0 = p0 + hb2[g * 2], l1 = p1 + hb2[g * 2 + 1];
    const float mx = fmaxf(l0, l1);
    const float e0 = expf(l0 - mx), e1 = expf(l1 - mx);
    const float inv = 1.f / (e0 + e1);
    out[(size_t)b * 32 + g * 2] = e0 * inv;
    out[(size_t)b * 32 + g * 2 + 1] = e1 * inv;
  }
}

// ---------------------------------------------------------------------------
extern "C" void kernel_launch(void* const* d_in, const int* in_sizes, int n_in,
                              void* d_out, int out_size, void* d_ws, size_t ws_size,
                              hipStream_t stream) {
  const float* x = (const float*)d_in[0];
  const float* proj_w = (const float*)d_in[1];
  const float* proj_b = (const float*)d_in[2];
  const float* wq = (const float*)d_in[3];
  const float* wk = (const float*)d_in[4];
  const float* wvv = (const float*)d_in[5];
  const float* bq = (const float*)d_in[6];
  const float* bk = (const float*)d_in[7];
  const float* bv = (const float*)d_in[8];
  const float* wo = (const float*)d_in[9];
  const float* bo = (const float*)d_in[10];
  const float* ln1_g = (const float*)d_in[11];
  const float* ln1_b = (const float*)d_in[12];
  const float* ln2_g = (const float*)d_in[13];
  const float* ln2_b = (const float*)d_in[14];
  const float* w1 = (const float*)d_in[15];
  const float* b1 = (const float*)d_in[16];
  const float* w2 = (const float*)d_in[17];
  const float* b2 = (const float*)d_in[18];
  const float* hw1 = (const float*)d_in[19];
  const float* hb1 = (const float*)d_in[20];
  const float* hw2 = (const float*)d_in[21];
  const float* hb2 = (const float*)d_in[22];
  float* out = (float*)d_out;
  char* ws = (char*)d_ws;

  // ---- workspace layout (bytes), lifetime-aliased ----
  size_t o = 0;
  auto take = [&](size_t bytes) { size_t r = o; o += bytes; return r; };
  const size_t o_wqkv = take(12582912);  // L*3072*1024 bf16 (q|k|v rows)
  const size_t o_wo = take(4194304);
  const size_t o_w1 = take(16777216);
  const size_t o_w2 = take(16777216);
  const size_t o_pw = take(1048576);
  const size_t o_h16 = take(16777216);
  const size_t o_pre = take(16777216);  // pre-LN, bf16
  const size_t o_r4 = take(67108864);   // {qkv(50.3M), vT(8.4M)} | ff1(64M)
  const size_t o_r5 = take(16777216);   // {x16, pe} | ctx
  const size_t o_z = take(262144);
  const size_t o_bqkv = take(24576);

  bf16_t* wqkv16 = (bf16_t*)(ws + o_wqkv);
  bf16_t* wo16 = (bf16_t*)(ws + o_wo);
  bf16_t* w1_16 = (bf16_t*)(ws + o_w1);
  bf16_t* w2_16 = (bf16_t*)(ws + o_w2);
  bf16_t* pw16 = (bf16_t*)(ws + o_pw);
  bf16_t* h16 = (bf16_t*)(ws + o_h16);
  bf16_t* pre16 = (bf16_t*)(ws + o_pre);
  bf16_t* qkv16 = (bf16_t*)(ws + o_r4);
  bf16_t* vT16 = (bf16_t*)(ws + o_r4 + 50331648);
  bf16_t* ff1 = (bf16_t*)(ws + o_r4);
  bf16_t* x16 = (bf16_t*)(ws + o_r5);
  float* pe32 = (float*)(ws + o_r5 + 8388608);
  bf16_t* ctx16 = (bf16_t*)(ws + o_r5);
  float* zbuf = (float*)(ws + o_z);
  float* bqkv = (float*)(ws + o_bqkv);

  // ---- merged prep: converts + PE + bias concat (one launch) ----
  prep_all<<<33304, 256, 0, stream>>>(x, proj_w, wq, wk, wvv, wo, w1, w2, bq, bk, bv,
                                      x16, pw16, wqkv16, wo16, w1_16, w2_16, pe32,
                                      bqkv);

  // ---- projection: h = x @ proj_w^T + proj_b + pe ----
  gemm9<2, 128, 128><<<dim3(8, 64), 256, 0, stream>>>(x16, pw16, proj_b, h16, nullptr,
                                                      pe32, nullptr, 8192, 1024, 512);

  for (int l = 0; l < 2; ++l) {
    const bf16_t* wqkv_l = wqkv16 + (size_t)l * 3145728;
    const bf16_t* wo_l = wo16 + (size_t)l * 1048576;
    const bf16_t* w1_l = w1_16 + (size_t)l * 4194304;
    const bf16_t* w2_l = w2_16 + (size_t)l * 4194304;

    // QKV with fused V-transpose (EPI=4): q,k -> qkv16; v -> vT16 transposed
    gemm9<4, 256, 128><<<dim3(24, 32), 512, 0, stream>>>(h16, wqkv_l, bqkv + l * 3072,
                                                         qkv16, nullptr, nullptr,
                                                         vT16, 8192, 3072, 1024);
    attn_kernel<<<dim3(16, 64), 256, 0, stream>>>(qkv16, vT16, ctx16);
    gemm9<3, 128, 128><<<dim3(8, 64), 256, 0, stream>>>(ctx16, wo_l, bo + l * 1024,
                                                        pre16, h16, nullptr, nullptr,
                                                        8192, 1024, 1024);
    ln_kernel<<<8192, 256, 0, stream>>>(pre16, ln1_g + l * 1024, ln1_b + l * 1024,
                                        h16);
    gemm9<1, 256, 256><<<dim3(16, 32), 512, 0, stream>>>(h16, w1_l, b1 + l * 4096, ff1,
                                                         nullptr, nullptr, nullptr,
                                                         8192, 4096, 1024);
    gemm9<3, 128, 128><<<dim3(8, 64), 256, 0, stream>>>(ff1, w2_l, b2 + l * 1024,
                                                        pre16, h16, nullptr, nullptr,
                                                        8192, 1024, 4096);
    ln_kernel<<<8192, 256, 0, stream>>>(pre16, ln2_g + l * 1024, ln2_b + l * 1024,
                                        h16);
  }

  // ---- head ----
  head_z<<<dim3(16, 16), 256, 0, stream>>>(h16, hw1, hb1, zbuf);
  head_logits<<<dim3(4, 16), 64, 0, stream>>>(zbuf, hw2, hb2, out);
}